// Round 1
// baseline (525.454 us; speedup 1.0000x reference)
//
#include <hip/hip_runtime.h>

// ---------------------------------------------------------------------------
// GCN stack: 2-layer GCN with symmetric normalization + self loops.
//   deg[v] = in_count[v] + 1 ; dinv = rsqrt(deg)
//   layer1: x1[v,c] = relu(W1[c] * (dinv[v] * (g[v] + sum_{e->v} g[src])) + b1[c])
//           with g[u] = dinv[u]*feat[u]    (feat is [n,1] so layer1 aggregates a SCALAR)
//   store   y[v,c] = dinv[v]*x1[v,c]
//   layer2: out[v,k] = relu( (dinv[v]*(y[v,:] + sum_{e->v} y[src,:])) @ W2 + b2 )
// CSR built on device via counting sort so both aggregations are gathers.
// ---------------------------------------------------------------------------

#define TPB 256

// Detect whether edge_ix arrived as int64 (low/high 32-bit pairs) or int32.
// Values are node ids in [0, 1e5) (non-negative, < 2^31) so int64 high words
// are exactly 0. Sample 2048 odd positions; all-zero => int64.
__global__ void k_detect(const int* __restrict__ e32, int E, int* __restrict__ flag) {
    __shared__ int ok;
    if (threadIdx.x == 0) ok = 1;
    __syncthreads();
    int stride = E / 2048; if (stride < 1) stride = 1;
    bool bad = false;
#pragma unroll
    for (int i = 0; i < 8; ++i) {
        long k = (long)(threadIdx.x * 8 + i) * stride + 1;
        if (k < E && e32[2 * k + 1] != 0) bad = true;   // idx 2k+1 < 2E: safe both ways
    }
    if (bad) atomicAnd(&ok, 0);
    __syncthreads();
    if (threadIdx.x == 0) *flag = ok;   // 1 => int64 layout (shift 1), 0 => int32
}

__global__ void k_zero(int* __restrict__ p, int n) {
    int i = blockIdx.x * TPB + threadIdx.x;
    if (i < n) p[i] = 0;
}

__global__ void k_count(const int* __restrict__ e32, const int* __restrict__ flag,
                        int E, int* __restrict__ cnt) {
    int e = blockIdx.x * TPB + threadIdx.x;
    if (e >= E) return;
    int sh = *flag;
    int d = e32[((long)E << sh) + ((long)e << sh)];
    atomicAdd(&cnt[d], 1);
}

__global__ void k_breduce(const int* __restrict__ cnt, int n, int* __restrict__ bsum) {
    __shared__ int sm[TPB];
    int idx = blockIdx.x * TPB + threadIdx.x;
    sm[threadIdx.x] = (idx < n) ? cnt[idx] : 0;
    __syncthreads();
    for (int off = TPB / 2; off > 0; off >>= 1) {
        if (threadIdx.x < off) sm[threadIdx.x] += sm[threadIdx.x + off];
        __syncthreads();
    }
    if (threadIdx.x == 0) bsum[blockIdx.x] = sm[0];
}

// exclusive scan of block sums (nB <= 512)
__global__ void k_bscan(const int* __restrict__ bsum, int nB, int* __restrict__ bOff) {
    __shared__ int sm[512];
    int t = threadIdx.x;
    int v = (t < nB) ? bsum[t] : 0;
    sm[t] = v;
    __syncthreads();
    for (int off = 1; off < 512; off <<= 1) {
        int x = sm[t];
        if (t >= off) x += sm[t - off];
        __syncthreads();
        sm[t] = x;
        __syncthreads();
    }
    if (t < nB) bOff[t] = sm[t] - v;
}

__global__ void k_cscan(const int* __restrict__ cnt, const int* __restrict__ bOff,
                        int n, int* __restrict__ rowptr, int* __restrict__ cursor) {
    __shared__ int sm[TPB];
    int idx = blockIdx.x * TPB + threadIdx.x;
    int v = (idx < n) ? cnt[idx] : 0;
    sm[threadIdx.x] = v;
    __syncthreads();
    for (int off = 1; off < TPB; off <<= 1) {
        int x = sm[threadIdx.x];
        if (threadIdx.x >= off) x += sm[threadIdx.x - off];
        __syncthreads();
        sm[threadIdx.x] = x;
        __syncthreads();
    }
    int excl = sm[threadIdx.x] - v + bOff[blockIdx.x];
    if (idx <= n) {
        rowptr[idx] = excl;            // rowptr[n] lands on total = E
        if (idx < n) cursor[idx] = excl;
    }
}

__global__ void k_fill(const int* __restrict__ e32, const int* __restrict__ flag,
                       int E, int* __restrict__ cursor, int* __restrict__ csr) {
    int e = blockIdx.x * TPB + threadIdx.x;
    if (e >= E) return;
    int sh = *flag;
    long ei = (long)e << sh;
    int s = e32[ei];
    int d = e32[((long)E << sh) + ei];
    int p = atomicAdd(&cursor[d], 1);
    csr[p] = s;
}

__global__ void k_prep(const float* __restrict__ feat, const int* __restrict__ cnt,
                       int n, float* __restrict__ dinv, float* __restrict__ g) {
    int v = blockIdx.x * TPB + threadIdx.x;
    if (v >= n) return;
    float di = rsqrtf((float)(cnt[v] + 1));
    dinv[v] = di;
    g[v] = di * feat[v];
}

// layer 1: scalar gather + 32-wide outer product; writes y = dinv * relu(...)
__global__ void k_l1(const float* __restrict__ g, const float* __restrict__ dinv,
                     const int* __restrict__ rowptr, const int* __restrict__ csr,
                     const float* __restrict__ W1, const float* __restrict__ b1,
                     int n, float* __restrict__ y) {
    int v = blockIdx.x * TPB + threadIdx.x;
    if (v >= n) return;
    float sum = g[v];                       // self loop
    int r0 = rowptr[v], r1 = rowptr[v + 1];
    int i = r0;
    for (; i + 3 < r1; i += 4) {
        int u0 = csr[i], u1 = csr[i + 1], u2 = csr[i + 2], u3 = csr[i + 3];
        sum += g[u0] + g[u1] + g[u2] + g[u3];
    }
    for (; i < r1; ++i) sum += g[csr[i]];
    float dv = dinv[v];
    float s = dv * sum;
    float4* yv = (float4*)(y + (size_t)v * 32);
    const float4* w4 = (const float4*)W1;
    const float4* b4 = (const float4*)b1;
#pragma unroll
    for (int q = 0; q < 8; ++q) {
        float4 w = w4[q], bb = b4[q], r;
        r.x = dv * fmaxf(w.x * s + bb.x, 0.f);
        r.y = dv * fmaxf(w.y * s + bb.y, 0.f);
        r.z = dv * fmaxf(w.z * s + bb.z, 0.f);
        r.w = dv * fmaxf(w.w * s + bb.w, 0.f);
        yv[q] = r;
    }
}

// layer 2: 8 nodes per 256-thread block; 32 lanes per node gather y rows
// (coalesced 128B reads), then 32x64 matmul from LDS.
__global__ void k_l2(const float* __restrict__ y, const int* __restrict__ rowptr,
                     const int* __restrict__ csr, const float* __restrict__ dinv,
                     const float* __restrict__ W2, const float* __restrict__ b2,
                     float* __restrict__ out, int n) {
    __shared__ float sW[32 * 64];
    __shared__ float sb[64];
    __shared__ float sagg[8][33];
    int t = threadIdx.x;
    for (int i = t; i < 32 * 64; i += TPB) sW[i] = W2[i];
    if (t < 64) sb[t] = b2[t];

    int vl = t >> 5;          // node slot in block (0..7)
    int c  = t & 31;          // feature column (0..31)
    int v  = blockIdx.x * 8 + vl;

    float acc = 0.f;
    if (v < n) {
        float dv = dinv[v];
        acc = y[v * 32 + c];                  // self loop
        int r0 = rowptr[v], r1 = rowptr[v + 1];
        int i = r0;
        for (; i + 3 < r1; i += 4) {
            int u0 = csr[i], u1 = csr[i + 1], u2 = csr[i + 2], u3 = csr[i + 3];
            acc += y[u0 * 32 + c];
            acc += y[u1 * 32 + c];
            acc += y[u2 * 32 + c];
            acc += y[u3 * 32 + c];
        }
        for (; i < r1; ++i) acc += y[csr[i] * 32 + c];
        acc *= dv;
    }
    sagg[vl][c] = acc;
    __syncthreads();

    if (v < n) {
        float o0 = sb[c], o1 = sb[c + 32];
#pragma unroll
        for (int j = 0; j < 32; ++j) {
            float a = sagg[vl][j];
            o0 += a * sW[j * 64 + c];
            o1 += a * sW[j * 64 + 32 + c];
        }
        out[v * 64 + c]      = fmaxf(o0, 0.f);
        out[v * 64 + 32 + c] = fmaxf(o1, 0.f);
    }
}

static inline size_t align256(size_t x) { return (x + 255) & ~(size_t)255; }

extern "C" void kernel_launch(void* const* d_in, const int* in_sizes, int n_in,
                              void* d_out, int out_size, void* d_ws, size_t ws_size,
                              hipStream_t stream) {
    const float* feat = (const float*)d_in[0];
    const int*   e32  = (const int*)d_in[1];
    const float* W1   = (const float*)d_in[2];
    const float* b1   = (const float*)d_in[3];
    const float* W2   = (const float*)d_in[4];
    const float* b2   = (const float*)d_in[5];
    float* out = (float*)d_out;

    int n  = in_sizes[0];        // 100000 (feat is [n,1])
    int E  = in_sizes[1] / 2;    // 3200000
    int nB = (n + TPB - 1) / TPB;

    char* w = (char*)d_ws;
    size_t off = 0;
    auto alloc = [&](size_t bytes) -> char* { char* p = w + off; off = align256(off + bytes); return p; };
    int*   csr    = (int*)alloc((size_t)E * 4);
    int*   cnt    = (int*)alloc((size_t)n * 4);
    int*   rowptr = (int*)alloc((size_t)(n + 1) * 4);
    int*   cursor = (int*)alloc((size_t)n * 4);
    int*   bsum   = (int*)alloc((size_t)nB * 4);
    int*   bOff   = (int*)alloc((size_t)nB * 4);
    int*   flag   = (int*)alloc(4);
    float* dinv   = (float*)alloc((size_t)n * 4);
    float* g      = (float*)alloc((size_t)n * 4);
    float* y      = (float*)alloc((size_t)n * 32 * 4);

    int gE  = (E + TPB - 1) / TPB;
    int gN  = (n + TPB - 1) / TPB;
    int gN1 = (n + 1 + TPB - 1) / TPB;

    hipLaunchKernelGGL(k_detect, dim3(1),   dim3(TPB), 0, stream, e32, E, flag);
    hipLaunchKernelGGL(k_zero,   dim3(gN),  dim3(TPB), 0, stream, cnt, n);
    hipLaunchKernelGGL(k_count,  dim3(gE),  dim3(TPB), 0, stream, e32, flag, E, cnt);
    hipLaunchKernelGGL(k_breduce,dim3(gN),  dim3(TPB), 0, stream, cnt, n, bsum);
    hipLaunchKernelGGL(k_bscan,  dim3(1),   dim3(512), 0, stream, bsum, nB, bOff);
    hipLaunchKernelGGL(k_cscan,  dim3(gN1), dim3(TPB), 0, stream, cnt, bOff, n, rowptr, cursor);
    hipLaunchKernelGGL(k_fill,   dim3(gE),  dim3(TPB), 0, stream, e32, flag, E, cursor, csr);
    hipLaunchKernelGGL(k_prep,   dim3(gN),  dim3(TPB), 0, stream, feat, cnt, n, dinv, g);
    hipLaunchKernelGGL(k_l1,     dim3(gN),  dim3(TPB), 0, stream, g, dinv, rowptr, csr, W1, b1, n, y);
    hipLaunchKernelGGL(k_l2,     dim3((n + 7) / 8), dim3(TPB), 0, stream, y, rowptr, csr, dinv, W2, b2, out, n);
}

// Round 2
// 207.507 us; speedup vs baseline: 2.5322x; 2.5322x over previous
//
#include <hip/hip_runtime.h>

// ---------------------------------------------------------------------------
// 2-layer GCN, symmetric norm + self loops.
//   layer1 aggregates a SCALAR (feat is [n,1]):
//     g[u] = dinv[u]*feat[u];  y[v,:] = dinv[v]*relu(W1*(dinv[v]*(g[v]+sum g[src])) + b1)
//   layer2: out[v,:] = relu((dinv[v]*(y[v,:]+sum y[src,:])) @ W2 + b2)
// CSR built per call via BUCKETED counting sort (bucket = dst>>6) so the
// scatter writes are clustered into ~1563 small hot regions that L2 can merge
// (the previous flat scatter produced 194MB of partial-line HBM writebacks).
// ---------------------------------------------------------------------------

#define TPB 256
#define NBMAX 4096   // max buckets held in LDS histograms (n <= 262144 @ shb=6)

// Detect int64 (low/high pairs) vs int32 edge layout: node ids < 2^31 so the
// int64 high words are exactly 0. Sample odd 32-bit positions.
__global__ void k_detect(const int* __restrict__ e32, int E, int* __restrict__ flag) {
    __shared__ int ok;
    if (threadIdx.x == 0) ok = 1;
    __syncthreads();
    int stride = E / 2048; if (stride < 1) stride = 1;
    bool bad = false;
#pragma unroll
    for (int i = 0; i < 8; ++i) {
        long k = (long)(threadIdx.x * 8 + i) * stride + 1;
        if (k < E && e32[2 * k + 1] != 0) bad = true;
    }
    if (bad) atomicAnd(&ok, 0);
    __syncthreads();
    if (threadIdx.x == 0) *flag = ok;   // 1 => int64, 0 => int32
}

__global__ void k_zero(int* __restrict__ p, int n) {
    int i = blockIdx.x * TPB + threadIdx.x;
    if (i < n) p[i] = 0;
}

// global bucket histogram (LDS-staged, few global atomics)
__global__ void k_hist(const int* __restrict__ e32, const int* __restrict__ flag,
                       int E, int NB, int shb, int* __restrict__ gHist) {
    __shared__ int sh[NBMAX];
    for (int i = threadIdx.x; i < NB; i += TPB) sh[i] = 0;
    __syncthreads();
    int f = *flag;
    int stride = gridDim.x * TPB;
    for (int e = blockIdx.x * TPB + threadIdx.x; e < E; e += stride) {
        int d = f ? ((const int2*)e32)[E + e].x : e32[E + e];
        atomicAdd(&sh[d >> shb], 1);
    }
    __syncthreads();
    for (int i = threadIdx.x; i < NB; i += TPB)
        if (sh[i]) atomicAdd(&gHist[i], sh[i]);
}

// one-block exclusive scan of NB bucket counts -> base, cursor; rowptr[n]=E
__global__ void k_scan(const int* __restrict__ gHist, int NB, int E,
                       int* __restrict__ base, int* __restrict__ cursor,
                       int* __restrict__ rowptr, int n) {
    __shared__ int s[TPB];
    int K = (NB + TPB - 1) / TPB;
    int t = threadIdx.x;
    int i0 = t * K;
    int tot = 0;
    for (int k = 0; k < K; ++k) { int i = i0 + k; if (i < NB) tot += gHist[i]; }
    s[t] = tot;
    __syncthreads();
    for (int off = 1; off < TPB; off <<= 1) {
        int v = s[t];
        int u = (t >= off) ? s[t - off] : 0;
        __syncthreads();
        s[t] = v + u;
        __syncthreads();
    }
    int run = s[t] - tot;   // exclusive
    for (int k = 0; k < K; ++k) {
        int i = i0 + k;
        if (i < NB) { int h = gHist[i]; base[i] = run; cursor[i] = run; run += h; }
    }
    if (t == 0) { base[NB] = E; rowptr[n] = E; }
}

// stage edges bucket-major: per-chunk LDS hist -> one reservation atomic per
// (bucket,block) -> scatter packed (src | (dst&((1<<shb)-1)) << (32-shb)).
__global__ void k_stage(const int* __restrict__ e32, const int* __restrict__ flag,
                        int E, int NB, int shb, int* __restrict__ cursor,
                        unsigned int* __restrict__ P, int chunk) {
    __shared__ int sh[NBMAX];
    int c0 = blockIdx.x * chunk;
    int c1 = c0 + chunk; if (c1 > E) c1 = E;
    for (int i = threadIdx.x; i < NB; i += TPB) sh[i] = 0;
    __syncthreads();
    int f = *flag;
    for (int e = c0 + threadIdx.x; e < c1; e += TPB) {
        int d = f ? ((const int2*)e32)[E + e].x : e32[E + e];
        atomicAdd(&sh[d >> shb], 1);
    }
    __syncthreads();
    for (int i = threadIdx.x; i < NB; i += TPB) {
        int c = sh[i];
        sh[i] = c ? atomicAdd(&cursor[i], c) : 0;   // LDS cell now holds cursor
    }
    __syncthreads();
    int lshift = 32 - shb;
    for (int e = c0 + threadIdx.x; e < c1; e += TPB) {
        int s, d;
        if (f) { s = ((const int2*)e32)[e].x; d = ((const int2*)e32)[E + e].x; }
        else   { s = e32[e];                  d = e32[E + e]; }
        int b = d >> shb;
        int pos = atomicAdd(&sh[b], 1);
        P[pos] = (unsigned)s | ((unsigned)(d & ((1 << shb) - 1)) << lshift);
    }
}

// one block per bucket: node-major sort within bucket (writes confined to an
// ~8KB window), plus rowptr / dinv / g for the bucket's nodes.
__global__ void k_build(const unsigned int* __restrict__ P, const int* __restrict__ base,
                        int shb, int n, const float* __restrict__ feat,
                        int* __restrict__ csr, int* __restrict__ rowptr,
                        float* __restrict__ dinv, float* __restrict__ g) {
    __shared__ int cnt[TPB];
    __shared__ int loc[TPB];
    int b = blockIdx.x;
    int nb = 1 << shb;              // nodes per bucket (<= TPB)
    int v0 = b << shb;
    int t = threadIdx.x;
    cnt[t] = 0;
    __syncthreads();
    int p0 = base[b], p1 = base[b + 1];
    int lshift = 32 - shb;
    unsigned mask = (1u << lshift) - 1;
    for (int p = p0 + t; p < p1; p += TPB) {
        unsigned e = P[p];
        atomicAdd(&cnt[e >> lshift], 1);
    }
    __syncthreads();
    int c = cnt[t];
    loc[t] = c;
    __syncthreads();
    for (int off = 1; off < TPB; off <<= 1) {
        int v = loc[t];
        int u = (t >= off) ? loc[t - off] : 0;
        __syncthreads();
        loc[t] = v + u;
        __syncthreads();
    }
    int excl = loc[t] - c;
    int v = v0 + t;
    if (t < nb && v < n) {
        rowptr[v] = p0 + excl;
        float di = rsqrtf((float)(c + 1));
        dinv[v] = di;
        g[v] = di * feat[v];
    }
    cnt[t] = p0 + excl;             // reuse as global cursor
    __syncthreads();
    for (int p = p0 + t; p < p1; p += TPB) {
        unsigned e = P[p];
        int node = e >> lshift;
        int pos = atomicAdd(&cnt[node], 1);
        csr[pos] = (int)(e & mask);
    }
}

// layer 1: scalar gather + 32-wide outer product; writes y = dinv * relu(...)
__global__ void k_l1(const float* __restrict__ g, const float* __restrict__ dinv,
                     const int* __restrict__ rowptr, const int* __restrict__ csr,
                     const float* __restrict__ W1, const float* __restrict__ b1,
                     int n, float* __restrict__ y) {
    int v = blockIdx.x * TPB + threadIdx.x;
    if (v >= n) return;
    float sum = g[v];
    int r0 = rowptr[v], r1 = rowptr[v + 1];
    int i = r0;
    for (; i + 3 < r1; i += 4) {
        int u0 = csr[i], u1 = csr[i + 1], u2 = csr[i + 2], u3 = csr[i + 3];
        sum += g[u0] + g[u1] + g[u2] + g[u3];
    }
    for (; i < r1; ++i) sum += g[csr[i]];
    float dv = dinv[v];
    float s = dv * sum;
    float4* yv = (float4*)(y + (size_t)v * 32);
    const float4* w4 = (const float4*)W1;
    const float4* b4 = (const float4*)b1;
#pragma unroll
    for (int q = 0; q < 8; ++q) {
        float4 w = w4[q], bb = b4[q], r;
        r.x = dv * fmaxf(w.x * s + bb.x, 0.f);
        r.y = dv * fmaxf(w.y * s + bb.y, 0.f);
        r.z = dv * fmaxf(w.z * s + bb.z, 0.f);
        r.w = dv * fmaxf(w.w * s + bb.w, 0.f);
        yv[q] = r;
    }
}

// layer 2: 8 nodes/block; 32 lanes per node gather y rows, then 32x64 matmul.
__global__ void k_l2(const float* __restrict__ y, const int* __restrict__ rowptr,
                     const int* __restrict__ csr, const float* __restrict__ dinv,
                     const float* __restrict__ W2, const float* __restrict__ b2,
                     float* __restrict__ out, int n) {
    __shared__ float sW[32 * 64];
    __shared__ float sb[64];
    __shared__ float sagg[8][33];
    int t = threadIdx.x;
    for (int i = t; i < 32 * 64; i += TPB) sW[i] = W2[i];
    if (t < 64) sb[t] = b2[t];

    int vl = t >> 5;
    int c  = t & 31;
    int v  = blockIdx.x * 8 + vl;

    float acc = 0.f;
    if (v < n) {
        float dv = dinv[v];
        acc = y[v * 32 + c];
        int r0 = rowptr[v], r1 = rowptr[v + 1];
        int i = r0;
        for (; i + 3 < r1; i += 4) {
            int u0 = csr[i], u1 = csr[i + 1], u2 = csr[i + 2], u3 = csr[i + 3];
            acc += y[u0 * 32 + c];
            acc += y[u1 * 32 + c];
            acc += y[u2 * 32 + c];
            acc += y[u3 * 32 + c];
        }
        for (; i < r1; ++i) acc += y[csr[i] * 32 + c];
        acc *= dv;
    }
    sagg[vl][c] = acc;
    __syncthreads();

    if (v < n) {
        float o0 = sb[c], o1 = sb[c + 32];
#pragma unroll
        for (int j = 0; j < 32; ++j) {
            float a = sagg[vl][j];
            o0 += a * sW[j * 64 + c];
            o1 += a * sW[j * 64 + 32 + c];
        }
        out[v * 64 + c]      = fmaxf(o0, 0.f);
        out[v * 64 + 32 + c] = fmaxf(o1, 0.f);
    }
}

static inline size_t align256(size_t x) { return (x + 255) & ~(size_t)255; }

extern "C" void kernel_launch(void* const* d_in, const int* in_sizes, int n_in,
                              void* d_out, int out_size, void* d_ws, size_t ws_size,
                              hipStream_t stream) {
    const float* feat = (const float*)d_in[0];
    const int*   e32  = (const int*)d_in[1];
    const float* W1   = (const float*)d_in[2];
    const float* b1   = (const float*)d_in[3];
    const float* W2   = (const float*)d_in[4];
    const float* b2   = (const float*)d_in[5];
    float* out = (float*)d_out;

    int n = in_sizes[0];         // 100000
    int E = in_sizes[1] / 2;     // 3200000

    int shb = 6;                                     // 64 nodes / bucket
    while ((((n + (1 << shb) - 1) >> shb) > NBMAX) && shb < 12) shb++;
    int NB = (n + (1 << shb) - 1) >> shb;            // 1563

    char* w = (char*)d_ws;
    size_t off = 0;
    auto alloc = [&](size_t bytes) -> char* { char* p = w + off; off = align256(off + bytes); return p; };
    size_t pbytes = (size_t)E * 4;
    size_t ybytes = (size_t)n * 32 * 4;
    unsigned int* P = (unsigned int*)alloc(pbytes > ybytes ? pbytes : ybytes);  // staging, then y
    int*   csr    = (int*)alloc((size_t)E * 4);
    int*   gHist  = (int*)alloc((size_t)NB * 4);
    int*   base   = (int*)alloc((size_t)(NB + 1) * 4);
    int*   cursor = (int*)alloc((size_t)NB * 4);
    int*   rowptr = (int*)alloc((size_t)(n + 1) * 4);
    float* dinv   = (float*)alloc((size_t)n * 4);
    float* g      = (float*)alloc((size_t)n * 4);
    int*   flag   = (int*)alloc(4);
    float* y      = (float*)P;                        // alias: P dead after k_build

    int chunk = (E + 255) / 256;                      // 256 staging blocks
    int gC = (E + chunk - 1) / chunk;
    int gN = (n + TPB - 1) / TPB;

    hipLaunchKernelGGL(k_detect, dim3(1),   dim3(TPB), 0, stream, e32, E, flag);
    hipLaunchKernelGGL(k_zero,   dim3((NB + TPB - 1) / TPB), dim3(TPB), 0, stream, gHist, NB);
    hipLaunchKernelGGL(k_hist,   dim3(256), dim3(TPB), 0, stream, e32, flag, E, NB, shb, gHist);
    hipLaunchKernelGGL(k_scan,   dim3(1),   dim3(TPB), 0, stream, gHist, NB, E, base, cursor, rowptr, n);
    hipLaunchKernelGGL(k_stage,  dim3(gC),  dim3(TPB), 0, stream, e32, flag, E, NB, shb, cursor, P, chunk);
    hipLaunchKernelGGL(k_build,  dim3(NB),  dim3(TPB), 0, stream, P, base, shb, n, feat, csr, rowptr, dinv, g);
    hipLaunchKernelGGL(k_l1,     dim3(gN),  dim3(TPB), 0, stream, g, dinv, rowptr, csr, W1, b1, n, y);
    hipLaunchKernelGGL(k_l2,     dim3((n + 7) / 8), dim3(TPB), 0, stream, y, rowptr, csr, dinv, W2, b2, out, n);
}